// Round 1
// 586.998 us; speedup vs baseline: 1.0038x; 1.0038x over previous
//
#include <hip/hip_runtime.h>
#include <math.h>

#define DIM 128
#define NEG_K 20

// Numerically stable log(sigmoid(x)) = min(x,0) - log1p(exp(-|x|))
__device__ __forceinline__ float log_sigmoid(float x) {
    float m = fminf(x, 0.0f);
    return m - log1pf(__expf(-fabsf(x)));
}

// One full wave (64 lanes) per batch element; lane holds float2 so one
// global_load_dwordx2 covers a full 512B embedding row (coalesced).
// All indices are wave-uniform and forced through SGPRs (readfirstlane):
//  - target/context/neg index loads become s_load (scalar path, issued once)
//  - row base addresses are SALU math (SGPR base + shared lane voffset)
//  - only gathered data occupies VGPRs: 2 VGPR/row in flight vs 4 before
// -> low VGPR pressure => max occupancy => ~22 loads in flight per wave,
// which is what a latency-bound random-gather kernel needs.
__global__ __launch_bounds__(256) void sgns_partial_kernel(
    const int* __restrict__ target,
    const int* __restrict__ context,
    const int* __restrict__ neg,
    const float* __restrict__ emb,
    float* __restrict__ partials,
    int B)
{
    const int lane = threadIdx.x & 63;
    const int wid  = __builtin_amdgcn_readfirstlane(
                         (blockIdx.x * blockDim.x + threadIdx.x) >> 6);
    const int nW   = (gridDim.x * blockDim.x) >> 6;

    float local = 0.0f;   // only lane 0 of each wave accumulates
    for (int b = wid; b < B; b += nW) {
        const int tgt = __builtin_amdgcn_readfirstlane(target[b]);
        const int ctx = __builtin_amdgcn_readfirstlane(context[b]);

        // 20 neg indices into SGPRs (uniform address -> s_load; the
        // readfirstlane guarantees downstream address math is scalar).
        int ni[NEG_K];
        const int* __restrict__ nb = neg + (size_t)b * NEG_K;
        #pragma unroll
        for (int k = 0; k < NEG_K; ++k)
            ni[k] = __builtin_amdgcn_readfirstlane(nb[k]);

        const float2 v = ((const float2*)(emb + (size_t)tgt * DIM))[lane];
        const float2 u = ((const float2*)(emb + (size_t)ctx * DIM))[lane];

        // sum_k dot(u_hat_k, v) == dot(sum_k u_hat_k, v): accumulate rows.
        float2 ns = make_float2(0.f, 0.f);
        #pragma unroll
        for (int k = 0; k < NEG_K; ++k) {
            const float2 un = ((const float2*)(emb + (size_t)ni[k] * DIM))[lane];
            ns.x += un.x; ns.y += un.y;
        }

        float pos = u.x * v.x + u.y * v.y;
        float ng  = ns.x * v.x + ns.y * v.y;

        // Reduce across the 64 lanes of the wave.
        #pragma unroll
        for (int off = 32; off; off >>= 1) {
            pos += __shfl_xor(pos, off);
            ng  += __shfl_xor(ng,  off);
        }
        if (lane == 0) local += log_sigmoid(pos) + log_sigmoid(-ng);
    }

    // One partial per block (no global atomics).
    __shared__ float wsum[4];
    if (lane == 0) wsum[threadIdx.x >> 6] = local;
    __syncthreads();
    if (threadIdx.x == 0)
        partials[blockIdx.x] = wsum[0] + wsum[1] + wsum[2] + wsum[3];
}

// Single-block reduction of the per-block partials; writes the final loss.
__global__ __launch_bounds__(256) void sgns_reduce_kernel(
    const float* __restrict__ partials, float* __restrict__ out,
    int n, float invB)
{
    float s = 0.0f;
    for (int i = threadIdx.x; i < n; i += 256) s += partials[i];
    #pragma unroll
    for (int off = 32; off; off >>= 1) s += __shfl_xor(s, off);

    __shared__ float wsum[4];
    const int lane = threadIdx.x & 63;
    if (lane == 0) wsum[threadIdx.x >> 6] = s;
    __syncthreads();
    if (threadIdx.x == 0)
        out[0] = -(wsum[0] + wsum[1] + wsum[2] + wsum[3]) * invB;
}

extern "C" void kernel_launch(void* const* d_in, const int* in_sizes, int n_in,
                              void* d_out, int out_size, void* d_ws, size_t ws_size,
                              hipStream_t stream) {
    const int*   target  = (const int*)d_in[0];
    const int*   context = (const int*)d_in[1];
    const int*   neg     = (const int*)d_in[2];
    const float* emb     = (const float*)d_in[3];
    float* out      = (float*)d_out;
    float* partials = (float*)d_ws;
    const int B = in_sizes[0];

    const int threads = 256;
    const int blocks  = (B + 3) / 4;   // one full wave per batch element

    sgns_partial_kernel<<<blocks, threads, 0, stream>>>(target, context, neg,
                                                        emb, partials, B);
    sgns_reduce_kernel<<<1, threads, 0, stream>>>(partials, out, blocks,
                                                  1.0f / (float)B);
}